// Round 4
// baseline (84.272 us; speedup 1.0000x reference)
//
#include <hip/hip_runtime.h>

// CenterLoss: out = mean_i ||x_i - centers[labels_i]||^2
// B=16384, D=512, C=4000.
//
// Round-4: unit-stride load pattern. Previously lane i loaded float4s at
// {lane*2, lane*2+1} (32B/lane stride -> each load instruction spans 2KB
// with 16B holes, 2x cacheline requests/instr). Now lane i loads float4s
// {lane, lane+64}: every global_load_dwordx4 is 64 lanes x 16B contiguous
// = 1KB unit-stride, the ideal coalescing shape.
// Structure unchanged from round-3 best (83.3us): 2048 blocks * 4 waves *
// 2 rows/wave, __launch_bounds__(256,8) to pin 8 waves/SIMD.

#define B_SIZE 16384
#define D_SIZE 512
#define S1_BLOCKS 2048   // 2048 blocks * 4 waves * 2 rows = 16384 rows

__global__ __launch_bounds__(256, 8) void center_loss_stage1(
    const float* __restrict__ x,
    const int* __restrict__ labels,
    const float* __restrict__ centers,
    float* __restrict__ partials) {

    const int lane = threadIdx.x & 63;
    const int wave = threadIdx.x >> 6;                 // 4 waves per block
    const int gw   = (blockIdx.x << 2) + wave;         // global wave id [0,8192)
    const int row0 = gw << 1;                          // 2 consecutive rows

    // both labels in one 8B wave-uniform load
    const int2 lab = *reinterpret_cast<const int2*>(labels + row0);

    // x: row r is 128 float4; lane i covers float4 {i, i+64} (unit-stride)
    const float4* x0 = reinterpret_cast<const float4*>(x)
                     + (size_t)row0 * 128 + lane;
    const float4* x1 = x0 + 128;

    const float4* cb = reinterpret_cast<const float4*>(centers);
    const float4* c0 = cb + (size_t)lab.x * 128 + lane;
    const float4* c1 = cb + (size_t)lab.y * 128 + lane;

    // issue all 8 loads before any use; each is 64x16B contiguous
    float4 xa0 = x0[0], xb0 = x0[64];
    float4 xa1 = x1[0], xb1 = x1[64];
    float4 ca0 = c0[0], cb0 = c0[64];
    float4 ca1 = c1[0], cb1 = c1[64];

    float acc = 0.0f, d;
    d = xa0.x - ca0.x; acc += d * d;
    d = xa0.y - ca0.y; acc += d * d;
    d = xa0.z - ca0.z; acc += d * d;
    d = xa0.w - ca0.w; acc += d * d;
    d = xb0.x - cb0.x; acc += d * d;
    d = xb0.y - cb0.y; acc += d * d;
    d = xb0.z - cb0.z; acc += d * d;
    d = xb0.w - cb0.w; acc += d * d;
    d = xa1.x - ca1.x; acc += d * d;
    d = xa1.y - ca1.y; acc += d * d;
    d = xa1.z - ca1.z; acc += d * d;
    d = xa1.w - ca1.w; acc += d * d;
    d = xb1.x - cb1.x; acc += d * d;
    d = xb1.y - cb1.y; acc += d * d;
    d = xb1.z - cb1.z; acc += d * d;
    d = xb1.w - cb1.w; acc += d * d;

    // wave-level reduction over 64 lanes
    #pragma unroll
    for (int off = 32; off > 0; off >>= 1)
        acc += __shfl_down(acc, off, 64);

    __shared__ float partial[4];
    if (lane == 0) partial[wave] = acc;
    __syncthreads();

    if (threadIdx.x == 0)
        partials[blockIdx.x] = (partial[0] + partial[1])
                             + (partial[2] + partial[3]);
}

__global__ __launch_bounds__(512) void center_loss_stage2(
    const float* __restrict__ partials,
    float* __restrict__ out) {

    const int t = threadIdx.x;
    const float4 v = reinterpret_cast<const float4*>(partials)[t];  // 512*4 = 2048
    float acc = (v.x + v.y) + (v.z + v.w);

    const int lane = t & 63;
    const int wave = t >> 6;   // 8 waves

    #pragma unroll
    for (int off = 32; off > 0; off >>= 1)
        acc += __shfl_down(acc, off, 64);

    __shared__ float partial[8];
    if (lane == 0) partial[wave] = acc;
    __syncthreads();

    if (t == 0) {
        float s = 0.0f;
        #pragma unroll
        for (int i = 0; i < 8; ++i) s += partial[i];
        out[0] = s * (1.0f / (float)B_SIZE);
    }
}

extern "C" void kernel_launch(void* const* d_in, const int* in_sizes, int n_in,
                              void* d_out, int out_size, void* d_ws, size_t ws_size,
                              hipStream_t stream) {
    const float* x       = (const float*)d_in[0];
    const int*   labels  = (const int*)d_in[1];
    const float* centers = (const float*)d_in[2];
    float* out      = (float*)d_out;
    float* partials = (float*)d_ws;   // 2048 floats = 8 KB scratch

    center_loss_stage1<<<S1_BLOCKS, 256, 0, stream>>>(x, labels, centers, partials);
    center_loss_stage2<<<1, 512, 0, stream>>>(partials, out);
}